// Round 19
// baseline (2058.068 us; speedup 1.0000x reference)
//
#include <hip/hip_runtime.h>

#define T_LEN 2048
#define HID 64
#define EMB 128
#define WD 8
#define NWIN (T_LEN / WD)    // 256
#define NPH (NWIN + 4)

typedef _Float16 half2_t __attribute__((ext_vector_type(2)));
typedef unsigned uint4v __attribute__((ext_vector_type(4)));

#if __has_builtin(__builtin_amdgcn_exp2f)
#define EXP2F(x) __builtin_amdgcn_exp2f(x)
#else
#define EXP2F(x) exp2f(x)
#endif
#if __has_builtin(__builtin_amdgcn_rcpf)
#define RCPF(x) __builtin_amdgcn_rcpf(x)
#else
#define RCPF(x) (1.0f / (x))
#endif

#define LOG2E 1.4426950408889634f

__device__ __forceinline__ float fdot2(unsigned a, unsigned b, float c) {
    return __builtin_amdgcn_fdot2(__builtin_bit_cast(half2_t, a),
                                  __builtin_bit_cast(half2_t, b), c, false);
}

// Full-row 64-MAC dot: 8 weight quads vs 8 gathered-h quads, 4 chains.
__device__ __forceinline__ float dotrow(const uint4v* w, const uint4v* g, float init) {
    float a0 = init, a1 = 0.f, a2 = 0.f, a3 = 0.f;
    #pragma unroll
    for (int q = 0; q < 8; ++q) {
        a0 = fdot2(w[q][0], g[q][0], a0);
        a1 = fdot2(w[q][1], g[q][1], a1);
        a2 = fdot2(w[q][2], g[q][2], a2);
        a3 = fdot2(w[q][3], g[q][3], a3);
    }
    return (a0 + a1) + (a2 + a3);
}

// Half-row 32-MAC dot: 4 weight quads vs 4 h quads, 2 chains.
__device__ __forceinline__ float dot16h(const uint4v* w, const uint4v* g) {
    float e = 0.f, o = 0.f;
    #pragma unroll
    for (int q = 0; q < 4; ++q) {
        e = fdot2(w[q][0], g[q][0], e);
        o = fdot2(w[q][1], g[q][1], o);
        e = fdot2(w[q][2], g[q][2], e);
        o = fdot2(w[q][3], g[q][3], o);
    }
    return e + o;
}

__device__ __forceinline__ uint4v pack8(float4 a, float4 b, float s) {
    half2_t h0{(_Float16)(a.x * s), (_Float16)(a.y * s)};
    half2_t h1{(_Float16)(a.z * s), (_Float16)(a.w * s)};
    half2_t h2{(_Float16)(b.x * s), (_Float16)(b.y * s)};
    half2_t h3{(_Float16)(b.z * s), (_Float16)(b.w * s)};
    uint4v q;
    q[0] = __builtin_bit_cast(unsigned, h0);
    q[1] = __builtin_bit_cast(unsigned, h1);
    q[2] = __builtin_bit_cast(unsigned, h2);
    q[3] = __builtin_bit_cast(unsigned, h3);
    return q;
}

// Full row (64 floats) -> 8 packed quads, exp2-prescaled.
__device__ __forceinline__ void cvt8(const float* __restrict__ Wp, float s, uint4v* dst) {
    const float4* p = reinterpret_cast<const float4*>(Wp);
    #pragma unroll
    for (int k = 0; k < 8; ++k) dst[k] = pack8(p[2 * k], p[2 * k + 1], s);
}
// Half row (32 floats) -> 4 packed quads.
__device__ __forceinline__ void cvt4(const float* __restrict__ Wp, float s, uint4v* dst) {
    const float4* p = reinterpret_cast<const float4*>(Wp);
    #pragma unroll
    for (int k = 0; k < 4; ++k) dst[k] = pack8(p[2 * k], p[2 * k + 1], s);
}

// ROUND 19 = R15 (977us best) at 3 waves/SIMD (768 thr, 12 waves). R18
// proved the C-wave recurrence is LATENCY-bound (VALUBusy fell 81->50% at
// the same wall when producer VALU work moved to MFMA): co-resident issuing
// waves ARE the latency hiding. This round deepens TLP: the 8 ih rows are
// re-cut so every SIMD carries 3 issuing waves and exactly 2560 dot-cyc
// per phase (wave->SIMD = wv%4):
//   S0: C0 | wih1_i k-lo (wv4) | wih1_i k-hi (wv8)
//   S1: C1 | wih1_f k-lo (wv5) | wih1_f k-hi (wv9)
//   S2: C2 | wih1_g k-lo (wv6) | wih1_g k-hi (wv10)
//   S3: wv3 = wih1_o + wih2_i | wv7 = wih2_{f,g} | wv11 = wih2_o
// K-split halves publish p1a (lo) / p1b (hi) at the same phase boundary --
// C1 sums both (no extra sync; unlike R13 there is no intra-step handoff).
// p1b class-3 slot is zeroed once at init (wv3 writes o fully into p1a).
// Schedule/barrier per phase unchanged from R15 (R16/R17: WD=16 and
// flag-sync both regress). waves_per_eu(3,3): VGPR cap ~168 >= C's ~116.
__global__ __launch_bounds__(768)
__attribute__((amdgpu_waves_per_eu(3, 3)))
void lstm3_fused(
    const float* __restrict__ x,
    const float* __restrict__ Wih0, const float* __restrict__ Whh0,
    const float* __restrict__ bih0, const float* __restrict__ bhh0,
    const float* __restrict__ Wih1, const float* __restrict__ Whh1,
    const float* __restrict__ bih1, const float* __restrict__ bhh1,
    const float* __restrict__ Wih2, const float* __restrict__ Whh2,
    const float* __restrict__ bih2, const float* __restrict__ bhh2,
    const float* __restrict__ fcW,  const float* __restrict__ fcb,
    float* __restrict__ out)
{
    const int b   = blockIdx.x;
    const int tid = threadIdx.x;
    const int wv  = tid >> 6;          // 0..11 (wave-uniform role)
    const int L   = tid & 63;

    __shared__ __align__(16) _Float16 h0ring[2 * WD][HID];
    __shared__ __align__(16) _Float16 h1ring[2 * WD][HID];
    __shared__ __align__(16) _Float16 h2ring[2][HID];
    __shared__ float p1a[2][WD][4][HID];   // wih1 k-lo partial (+ full o row)
    __shared__ float p1b[2][WD][4][HID];   // wih1 k-hi partial ([3] stays 0)
    __shared__ float p2buf[2][WD][4][HID];
    __shared__ __align__(16) float xs[T_LEN];

    {
        const float4* xg4 = reinterpret_cast<const float4*>(x + b * T_LEN);
        if (tid < 512) {
            reinterpret_cast<float4*>(xs)[tid] = xg4[tid];
            reinterpret_cast<unsigned*>(h0ring)[tid] = 0u;
            reinterpret_cast<unsigned*>(h1ring)[tid] = 0u;
        }
        if (tid < 64) reinterpret_cast<unsigned*>(h2ring)[tid] = 0u;
        float* pz = &p1b[0][0][0][0];
        for (int i = tid; i < 2 * WD * 4 * HID; i += 768) pz[i] = 0.f;
    }

    const float sI = -LOG2E, sF = -LOG2E, sG = -2.f * LOG2E, sO = -LOG2E;
    const float scl[4] = {sI, sF, sG, sO};

    uint4v w[4][8];                    // C: 4 whh rows; producers: subsets
    float bias4[4] = {0.f, 0.f, 0.f, 0.f};
    float wx4[4]   = {0.f, 0.f, 0.f, 0.f};

    if (wv < 3) {                      // C_l: whh_l all 4 gate rows
        const float* Wh = (wv == 0) ? Whh0 : (wv == 1) ? Whh1 : Whh2;
        const float* bi = (wv == 0) ? bih0 : (wv == 1) ? bih1 : bih2;
        const float* bh = (wv == 0) ? bhh0 : (wv == 1) ? bhh1 : bhh2;
        #pragma unroll
        for (int c = 0; c < 4; ++c) {
            cvt8(Wh + (c * 64 + L) * 64, scl[c], w[c]);
            bias4[c] = (bi[c * 64 + L] + bh[c * 64 + L]) * scl[c];
        }
        if (wv == 0) {
            #pragma unroll
            for (int c = 0; c < 4; ++c) wx4[c] = Wih0[c * 64 + L] * scl[c];
        }
    } else if (wv == 4 || wv == 5 || wv == 6) {       // wih1 c k-lo half
        const int c = wv - 4;
        cvt4(Wih1 + (c * 64 + L) * 64, scl[c], w[0]);
    } else if (wv == 8 || wv == 9 || wv == 10) {      // wih1 c k-hi half
        const int c = wv - 8;
        cvt4(Wih1 + (c * 64 + L) * 64 + 32, scl[c], w[0]);
    } else if (wv == 3) {              // wih1_o full + wih2_i full
        cvt8(Wih1 + (192 + L) * 64, sO, w[0]);
        cvt8(Wih2 + (  0 + L) * 64, sI, w[1]);
    } else if (wv == 7) {              // wih2_f + wih2_g
        cvt8(Wih2 + ( 64 + L) * 64, sF, w[0]);
        cvt8(Wih2 + (128 + L) * 64, sG, w[1]);
    } else {                           // wv == 11: wih2_o
        cvt8(Wih2 + (192 + L) * 64, sO, w[0]);
    }

    float cst = 0.f;
    __syncthreads();

    for (int ph = 0; ph < NPH; ++ph) {
        const int par = ph & 1;

        if (wv == 0) {
            if (ph < NWIN) {           // h0 window ph
                _Float16* cur = &h0ring[par * WD][0];
                const _Float16* prv = &h0ring[(par ^ 1) * WD][0];
                const int tb = ph * WD;
                #pragma unroll
                for (int j = 0; j < WD; ++j) {
                    const uint4v* hp = reinterpret_cast<const uint4v*>(
                        (j == 0) ? (prv + (WD - 1) * HID) : (cur + (j - 1) * HID));
                    uint4v g[8];
                    #pragma unroll
                    for (int k = 0; k < 8; ++k) g[k] = hp[k];
                    float xv = xs[tb + j];
                    float d0 = dotrow(w[0], g, fmaf(wx4[0], xv, bias4[0]));
                    float d1 = dotrow(w[1], g, fmaf(wx4[1], xv, bias4[1]));
                    float d2 = dotrow(w[2], g, fmaf(wx4[2], xv, bias4[2]));
                    float d3 = dotrow(w[3], g, fmaf(wx4[3], xv, bias4[3]));
                    float ai = RCPF(1.f + EXP2F(d0));
                    float af = RCPF(1.f + EXP2F(d1));
                    float ag = fmaf(2.f, RCPF(1.f + EXP2F(d2)), -1.f);
                    float ao = RCPF(1.f + EXP2F(d3));
                    cst = fmaf(af, cst, ai * ag);
                    float tc = fmaf(2.f, RCPF(1.f + EXP2F(-2.f * LOG2E * cst)), -1.f);
                    cur[j * HID + L] = (_Float16)(ao * tc);
                }
            }
        } else if (wv == 1) {
            if (ph >= 2 && ph < NWIN + 2) {    // h1 window ph-2
                _Float16* cur = &h1ring[par * WD][0];
                const _Float16* prv = &h1ring[(par ^ 1) * WD][0];
                const float (*pa)[4][HID] = p1a[par];
                const float (*pb)[4][HID] = p1b[par];
                #pragma unroll
                for (int j = 0; j < WD; ++j) {
                    const uint4v* hp = reinterpret_cast<const uint4v*>(
                        (j == 0) ? (prv + (WD - 1) * HID) : (cur + (j - 1) * HID));
                    uint4v g[8];
                    #pragma unroll
                    for (int k = 0; k < 8; ++k) g[k] = hp[k];
                    float d0 = dotrow(w[0], g, bias4[0] + pa[j][0][L] + pb[j][0][L]);
                    float d1 = dotrow(w[1], g, bias4[1] + pa[j][1][L] + pb[j][1][L]);
                    float d2 = dotrow(w[2], g, bias4[2] + pa[j][2][L] + pb[j][2][L]);
                    float d3 = dotrow(w[3], g, bias4[3] + pa[j][3][L] + pb[j][3][L]);
                    float ai = RCPF(1.f + EXP2F(d0));
                    float af = RCPF(1.f + EXP2F(d1));
                    float ag = fmaf(2.f, RCPF(1.f + EXP2F(d2)), -1.f);
                    float ao = RCPF(1.f + EXP2F(d3));
                    cst = fmaf(af, cst, ai * ag);
                    float tc = fmaf(2.f, RCPF(1.f + EXP2F(-2.f * LOG2E * cst)), -1.f);
                    cur[j * HID + L] = (_Float16)(ao * tc);
                }
            }
        } else if (wv == 2) {
            if (ph >= 4) {                     // h2 window ph-4
                const float (*pb)[4][HID] = p2buf[par];
                #pragma unroll
                for (int j = 0; j < WD; ++j) {
                    const uint4v* hp = reinterpret_cast<const uint4v*>(
                        &h2ring[(j & 1) ^ 1][0]);
                    uint4v g[8];
                    #pragma unroll
                    for (int k = 0; k < 8; ++k) g[k] = hp[k];
                    float d0 = dotrow(w[0], g, bias4[0] + pb[j][0][L]);
                    float d1 = dotrow(w[1], g, bias4[1] + pb[j][1][L]);
                    float d2 = dotrow(w[2], g, bias4[2] + pb[j][2][L]);
                    float d3 = dotrow(w[3], g, bias4[3] + pb[j][3][L]);
                    float ai = RCPF(1.f + EXP2F(d0));
                    float af = RCPF(1.f + EXP2F(d1));
                    float ag = fmaf(2.f, RCPF(1.f + EXP2F(d2)), -1.f);
                    float ao = RCPF(1.f + EXP2F(d3));
                    cst = fmaf(af, cst, ai * ag);
                    float tc = fmaf(2.f, RCPF(1.f + EXP2F(-2.f * LOG2E * cst)), -1.f);
                    h2ring[j & 1][L] = (_Float16)(ao * tc);
                }
            }
        } else {
            const bool p1act = (ph >= 1 && ph < NWIN + 1);
            const bool p2act = (ph >= 3 && ph < NWIN + 3);
            if (wv == 4 || wv == 5 || wv == 6) {       // wih1 k-lo halves
                if (p1act) {
                    const _Float16* hw = &h0ring[(par ^ 1) * WD][0];
                    float (*po)[4][HID] = p1a[par ^ 1];
                    const int c = wv - 4;
                    #pragma unroll
                    for (int j = 0; j < WD; ++j) {
                        const uint4v* hp = reinterpret_cast<const uint4v*>(hw + j * HID);
                        uint4v g[4];
                        #pragma unroll
                        for (int k = 0; k < 4; ++k) g[k] = hp[k];
                        po[j][c][L] = dot16h(w[0], g);
                    }
                }
            } else if (wv == 8 || wv == 9 || wv == 10) { // wih1 k-hi halves
                if (p1act) {
                    const _Float16* hw = &h0ring[(par ^ 1) * WD][0];
                    float (*po)[4][HID] = p1b[par ^ 1];
                    const int c = wv - 8;
                    #pragma unroll
                    for (int j = 0; j < WD; ++j) {
                        const uint4v* hp = reinterpret_cast<const uint4v*>(hw + j * HID) + 4;
                        uint4v g[4];
                        #pragma unroll
                        for (int k = 0; k < 4; ++k) g[k] = hp[k];
                        po[j][c][L] = dot16h(w[0], g);
                    }
                }
            } else if (wv == 3) {
                if (p1act) {                   // wih1_o full row
                    const _Float16* hw = &h0ring[(par ^ 1) * WD][0];
                    float (*po)[4][HID] = p1a[par ^ 1];
                    #pragma unroll
                    for (int j = 0; j < WD; ++j) {
                        const uint4v* hp = reinterpret_cast<const uint4v*>(hw + j * HID);
                        uint4v g[8];
                        #pragma unroll
                        for (int k = 0; k < 8; ++k) g[k] = hp[k];
                        po[j][3][L] = dotrow(w[0], g, 0.f);
                    }
                }
                if (p2act) {                   // wih2_i
                    const _Float16* hw = &h1ring[(par ^ 1) * WD][0];
                    float (*po)[4][HID] = p2buf[par ^ 1];
                    #pragma unroll
                    for (int j = 0; j < WD; ++j) {
                        const uint4v* hp = reinterpret_cast<const uint4v*>(hw + j * HID);
                        uint4v g[8];
                        #pragma unroll
                        for (int k = 0; k < 8; ++k) g[k] = hp[k];
                        po[j][0][L] = dotrow(w[1], g, 0.f);
                    }
                }
            } else if (wv == 7) {
                if (p2act) {                   // wih2_f, wih2_g
                    const _Float16* hw = &h1ring[(par ^ 1) * WD][0];
                    float (*po)[4][HID] = p2buf[par ^ 1];
                    #pragma unroll
                    for (int j = 0; j < WD; ++j) {
                        const uint4v* hp = reinterpret_cast<const uint4v*>(hw + j * HID);
                        uint4v g[8];
                        #pragma unroll
                        for (int k = 0; k < 8; ++k) g[k] = hp[k];
                        po[j][1][L] = dotrow(w[0], g, 0.f);
                        po[j][2][L] = dotrow(w[1], g, 0.f);
                    }
                }
            } else {                           // wv == 11: wih2_o
                if (p2act) {
                    const _Float16* hw = &h1ring[(par ^ 1) * WD][0];
                    float (*po)[4][HID] = p2buf[par ^ 1];
                    #pragma unroll
                    for (int j = 0; j < WD; ++j) {
                        const uint4v* hp = reinterpret_cast<const uint4v*>(hw + j * HID);
                        uint4v g[8];
                        #pragma unroll
                        for (int k = 0; k < 8; ++k) g[k] = hp[k];
                        po[j][3][L] = dotrow(w[0], g, 0.f);
                    }
                }
            }
        }

        __syncthreads();   // publish window: h rings + p-buffers
    }

    // Final FC (f32): h2[2047] -> slot 7&1 = 1.
    if (tid < EMB) {
        float acc = fcb[tid];
        const _Float16* hf = &h2ring[1][0];
        const float4* W4 = reinterpret_cast<const float4*>(fcW + tid * HID);
        #pragma unroll
        for (int k = 0; k < 16; ++k) {
            float4 wv4 = W4[k];
            acc = fmaf(wv4.x, (float)hf[4 * k + 0], acc);
            acc = fmaf(wv4.y, (float)hf[4 * k + 1], acc);
            acc = fmaf(wv4.z, (float)hf[4 * k + 2], acc);
            acc = fmaf(wv4.w, (float)hf[4 * k + 3], acc);
        }
        out[b * EMB + tid] = acc;
    }
}

extern "C" void kernel_launch(void* const* d_in, const int* in_sizes, int n_in,
                              void* d_out, int out_size, void* d_ws, size_t ws_size,
                              hipStream_t stream) {
    const float* x    = (const float*)d_in[0];
    const float* Wih0 = (const float*)d_in[1];
    const float* Whh0 = (const float*)d_in[2];
    const float* bih0 = (const float*)d_in[3];
    const float* bhh0 = (const float*)d_in[4];
    const float* Wih1 = (const float*)d_in[5];
    const float* Whh1 = (const float*)d_in[6];
    const float* bih1 = (const float*)d_in[7];
    const float* bhh1 = (const float*)d_in[8];
    const float* Wih2 = (const float*)d_in[9];
    const float* Whh2 = (const float*)d_in[10];
    const float* bih2 = (const float*)d_in[11];
    const float* bhh2 = (const float*)d_in[12];
    const float* fcW  = (const float*)d_in[13];
    const float* fcb  = (const float*)d_in[14];
    float* out = (float*)d_out;

    lstm3_fused<<<dim3(256), dim3(768), 0, stream>>>(
        x, Wih0, Whh0, bih0, bhh0,
        Wih1, Whh1, bih1, bhh1,
        Wih2, Whh2, bih2, bhh2,
        fcW, fcb, out);
}

// Round 20
// 986.072 us; speedup vs baseline: 2.0871x; 2.0871x over previous
//
#include <hip/hip_runtime.h>

#define T_LEN 2048
#define HID 64
#define EMB 128
#define WD 8
#define NWIN (T_LEN / WD)    // 256
#define NPH (NWIN + 4)

typedef _Float16 half2_t __attribute__((ext_vector_type(2)));
typedef unsigned uint4v __attribute__((ext_vector_type(4)));

#if __has_builtin(__builtin_amdgcn_exp2f)
#define EXP2F(x) __builtin_amdgcn_exp2f(x)
#else
#define EXP2F(x) exp2f(x)
#endif
#if __has_builtin(__builtin_amdgcn_rcpf)
#define RCPF(x) __builtin_amdgcn_rcpf(x)
#else
#define RCPF(x) (1.0f / (x))
#endif

#define LOG2E 1.4426950408889634f

__device__ __forceinline__ float fdot2(unsigned a, unsigned b, float c) {
    return __builtin_amdgcn_fdot2(__builtin_bit_cast(half2_t, a),
                                  __builtin_bit_cast(half2_t, b), c, false);
}

// Full-row 64-MAC dot: 8 weight quads vs 8 gathered-h quads, 4 chains.
__device__ __forceinline__ float dotrow(const uint4v* w, const uint4v* g, float init) {
    float a0 = init, a1 = 0.f, a2 = 0.f, a3 = 0.f;
    #pragma unroll
    for (int q = 0; q < 8; ++q) {
        a0 = fdot2(w[q][0], g[q][0], a0);
        a1 = fdot2(w[q][1], g[q][1], a1);
        a2 = fdot2(w[q][2], g[q][2], a2);
        a3 = fdot2(w[q][3], g[q][3], a3);
    }
    return (a0 + a1) + (a2 + a3);
}

__device__ __forceinline__ uint4v pack8(float4 a, float4 b, float s) {
    half2_t h0{(_Float16)(a.x * s), (_Float16)(a.y * s)};
    half2_t h1{(_Float16)(a.z * s), (_Float16)(a.w * s)};
    half2_t h2{(_Float16)(b.x * s), (_Float16)(b.y * s)};
    half2_t h3{(_Float16)(b.z * s), (_Float16)(b.w * s)};
    uint4v q;
    q[0] = __builtin_bit_cast(unsigned, h0);
    q[1] = __builtin_bit_cast(unsigned, h1);
    q[2] = __builtin_bit_cast(unsigned, h2);
    q[3] = __builtin_bit_cast(unsigned, h3);
    return q;
}

// One 64-float weight row -> 8 packed quads, exp2-space prescaled.
__device__ __forceinline__ void cvt8(const float* __restrict__ Wp, float s, uint4v* dst) {
    const float4* p = reinterpret_cast<const float4*>(Wp);
    #pragma unroll
    for (int k = 0; k < 8; ++k) dst[k] = pack8(p[2 * k], p[2 * k + 1], s);
}

// ROUND 20 = ROUND 15 (977us session best: WD=8, one barrier/phase,
// SIMD-balanced roles) with the p-buffers re-laid LANE-MAJOR so the C-waves'
// gate-init becomes ONE ds_read_b128 instead of 4 scalar reads (critical-
// path issue slots), at the cost of stride-4 producer writes (8-way bank
// aliasing - producers have barrier slack). Class->position swizzle
// (compile-time, free at the float4 unpack): c1->0, c2->1, c3->2, c0->3,
// chosen so wv7's class{1,2} pair is 8B-aligned -> one ds_write_b64.
// Everything else identical to R15. [R16 WD=16, R17 flag-sync, R18 MFMA
// offload, R19 3-waves/SIMD: all regressed - see session journal. The RA
// caps this family at 128 arch VGPRs regardless of waves_per_eu (R8/R19).]
// Roles: wv0/1/2 = C0/C1/C2 (4 whh rows in-lane, scalar cell)  [S0/S1/S2]
//        wv4 = wih1_i, wv5 = wih1_f, wv6 = wih1_g               [S0/S1/S2]
//        wv3 = wih1_o + wih2_i | wv7 = wih2_{f,g,o}             [S3]
// Schedule: phase ph: C0 h0[ph] | p1 for ph-1 | C1 h1[ph-2] | p2 for ph-3 |
// C2 h2[ph-4]. One barrier/phase; C recurrence is wave-private in-window.
__global__ __launch_bounds__(512)
__attribute__((amdgpu_waves_per_eu(2, 2)))
void lstm3_fused(
    const float* __restrict__ x,
    const float* __restrict__ Wih0, const float* __restrict__ Whh0,
    const float* __restrict__ bih0, const float* __restrict__ bhh0,
    const float* __restrict__ Wih1, const float* __restrict__ Whh1,
    const float* __restrict__ bih1, const float* __restrict__ bhh1,
    const float* __restrict__ Wih2, const float* __restrict__ Whh2,
    const float* __restrict__ bih2, const float* __restrict__ bhh2,
    const float* __restrict__ fcW,  const float* __restrict__ fcb,
    float* __restrict__ out)
{
    const int b   = blockIdx.x;
    const int tid = threadIdx.x;
    const int wv  = tid >> 6;          // 0..7 (wave-uniform role)
    const int L   = tid & 63;          // owned h-index / row-lane

    __shared__ __align__(16) _Float16 h0ring[2 * WD][HID];
    __shared__ __align__(16) _Float16 h1ring[2 * WD][HID];
    __shared__ __align__(16) _Float16 h2ring[2][HID];
    // Lane-major p-buffers: [parity][j][L*4 + pos]; pos: c1->0,c2->1,c3->2,c0->3.
    __shared__ __align__(16) float p1buf[2][WD][4 * HID];
    __shared__ __align__(16) float p2buf[2][WD][4 * HID];
    __shared__ __align__(16) float xs[T_LEN];

    // Stage x[b,0,:] (512 float4 by 512 threads); zero the rings.
    {
        const float4* xg4 = reinterpret_cast<const float4*>(x + b * T_LEN);
        reinterpret_cast<float4*>(xs)[tid] = xg4[tid];
        reinterpret_cast<unsigned*>(h0ring)[tid] = 0u;   // 512 dwords
        reinterpret_cast<unsigned*>(h1ring)[tid] = 0u;
        if (tid < 64) reinterpret_cast<unsigned*>(h2ring)[tid] = 0u;
    }

    const float sI = -LOG2E, sF = -LOG2E, sG = -2.f * LOG2E, sO = -LOG2E;
    const float scl[4] = {sI, sF, sG, sO};

    uint4v w[4][8];                    // C: 4 whh rows; wv3: 2; wv7: 3
    float bias4[4] = {0.f, 0.f, 0.f, 0.f};
    float wx4[4]   = {0.f, 0.f, 0.f, 0.f};

    if (wv < 3) {                      // C_l: whh_l all 4 gate rows
        const float* Wh = (wv == 0) ? Whh0 : (wv == 1) ? Whh1 : Whh2;
        const float* bi = (wv == 0) ? bih0 : (wv == 1) ? bih1 : bih2;
        const float* bh = (wv == 0) ? bhh0 : (wv == 1) ? bhh1 : bhh2;
        #pragma unroll
        for (int c = 0; c < 4; ++c) {
            cvt8(Wh + (c * 64 + L) * 64, scl[c], w[c]);
            bias4[c] = (bi[c * 64 + L] + bh[c * 64 + L]) * scl[c];
        }
        if (wv == 0) {
            #pragma unroll
            for (int c = 0; c < 4; ++c) wx4[c] = Wih0[c * 64 + L] * scl[c];
        }
    } else if (wv == 4) {              // P: wih1_i
        cvt8(Wih1 + (  0 + L) * 64, sI, w[0]);
    } else if (wv == 5) {              // P: wih1_f
        cvt8(Wih1 + ( 64 + L) * 64, sF, w[0]);
    } else if (wv == 6) {              // P: wih1_g
        cvt8(Wih1 + (128 + L) * 64, sG, w[0]);
    } else if (wv == 3) {              // P: wih1_o + wih2_i
        cvt8(Wih1 + (192 + L) * 64, sO, w[0]);
        cvt8(Wih2 + (  0 + L) * 64, sI, w[1]);
    } else {                           // wv == 7: wih2_{f,g,o}
        cvt8(Wih2 + ( 64 + L) * 64, sF, w[0]);
        cvt8(Wih2 + (128 + L) * 64, sG, w[1]);
        cvt8(Wih2 + (192 + L) * 64, sO, w[2]);
    }

    float cst = 0.f;                   // cell state (C waves, lane-local)
    __syncthreads();

    for (int ph = 0; ph < NPH; ++ph) {
        const int par = ph & 1;

        if (wv == 0) {
            if (ph < NWIN) {           // h0 window ph
                _Float16* cur = &h0ring[par * WD][0];
                const _Float16* prv = &h0ring[(par ^ 1) * WD][0];
                const int tb = ph * WD;
                #pragma unroll
                for (int j = 0; j < WD; ++j) {
                    const uint4v* hp = reinterpret_cast<const uint4v*>(
                        (j == 0) ? (prv + (WD - 1) * HID) : (cur + (j - 1) * HID));
                    uint4v g[8];
                    #pragma unroll
                    for (int k = 0; k < 8; ++k) g[k] = hp[k];
                    float xv = xs[tb + j];
                    float d0 = dotrow(w[0], g, fmaf(wx4[0], xv, bias4[0]));
                    float d1 = dotrow(w[1], g, fmaf(wx4[1], xv, bias4[1]));
                    float d2 = dotrow(w[2], g, fmaf(wx4[2], xv, bias4[2]));
                    float d3 = dotrow(w[3], g, fmaf(wx4[3], xv, bias4[3]));
                    float ai = RCPF(1.f + EXP2F(d0));
                    float af = RCPF(1.f + EXP2F(d1));
                    float ag = fmaf(2.f, RCPF(1.f + EXP2F(d2)), -1.f);
                    float ao = RCPF(1.f + EXP2F(d3));
                    cst = fmaf(af, cst, ai * ag);
                    float tc = fmaf(2.f, RCPF(1.f + EXP2F(-2.f * LOG2E * cst)), -1.f);
                    cur[j * HID + L] = (_Float16)(ao * tc);
                }
            }
        } else if (wv == 1) {
            if (ph >= 2 && ph < NWIN + 2) {    // h1 window ph-2
                _Float16* cur = &h1ring[par * WD][0];
                const _Float16* prv = &h1ring[(par ^ 1) * WD][0];
                const float (*pb)[4 * HID] = p1buf[par];
                #pragma unroll
                for (int j = 0; j < WD; ++j) {
                    const uint4v* hp = reinterpret_cast<const uint4v*>(
                        (j == 0) ? (prv + (WD - 1) * HID) : (cur + (j - 1) * HID));
                    uint4v g[8];
                    #pragma unroll
                    for (int k = 0; k < 8; ++k) g[k] = hp[k];
                    // One b128: pv = [c1, c2, c3, c0] (swizzled positions).
                    float4 pv = *reinterpret_cast<const float4*>(&pb[j][L * 4]);
                    float d0 = dotrow(w[0], g, bias4[0] + pv.w);
                    float d1 = dotrow(w[1], g, bias4[1] + pv.x);
                    float d2 = dotrow(w[2], g, bias4[2] + pv.y);
                    float d3 = dotrow(w[3], g, bias4[3] + pv.z);
                    float ai = RCPF(1.f + EXP2F(d0));
                    float af = RCPF(1.f + EXP2F(d1));
                    float ag = fmaf(2.f, RCPF(1.f + EXP2F(d2)), -1.f);
                    float ao = RCPF(1.f + EXP2F(d3));
                    cst = fmaf(af, cst, ai * ag);
                    float tc = fmaf(2.f, RCPF(1.f + EXP2F(-2.f * LOG2E * cst)), -1.f);
                    cur[j * HID + L] = (_Float16)(ao * tc);
                }
            }
        } else if (wv == 2) {
            if (ph >= 4) {                     // h2 window ph-4
                const float (*pb)[4 * HID] = p2buf[par];
                #pragma unroll
                for (int j = 0; j < WD; ++j) {
                    const uint4v* hp = reinterpret_cast<const uint4v*>(
                        &h2ring[(j & 1) ^ 1][0]);
                    uint4v g[8];
                    #pragma unroll
                    for (int k = 0; k < 8; ++k) g[k] = hp[k];
                    float4 pv = *reinterpret_cast<const float4*>(&pb[j][L * 4]);
                    float d0 = dotrow(w[0], g, bias4[0] + pv.w);
                    float d1 = dotrow(w[1], g, bias4[1] + pv.x);
                    float d2 = dotrow(w[2], g, bias4[2] + pv.y);
                    float d3 = dotrow(w[3], g, bias4[3] + pv.z);
                    float ai = RCPF(1.f + EXP2F(d0));
                    float af = RCPF(1.f + EXP2F(d1));
                    float ag = fmaf(2.f, RCPF(1.f + EXP2F(d2)), -1.f);
                    float ao = RCPF(1.f + EXP2F(d3));
                    cst = fmaf(af, cst, ai * ag);
                    float tc = fmaf(2.f, RCPF(1.f + EXP2F(-2.f * LOG2E * cst)), -1.f);
                    h2ring[j & 1][L] = (_Float16)(ao * tc);
                }
            }
        } else {
            const bool p1act = (ph >= 1 && ph < NWIN + 1);
            const bool p2act = (ph >= 3 && ph < NWIN + 3);
            if (wv == 4 || wv == 5 || wv == 6) {
                if (p1act) {                   // one wih1 row vs h0 window ph-1
                    const _Float16* hw = &h0ring[(par ^ 1) * WD][0];
                    float (*po)[4 * HID] = p1buf[par ^ 1];
                    // pos(c): c0->3, c1->0, c2->1
                    const int pos = (wv == 4) ? 3 : (wv - 5);
                    #pragma unroll
                    for (int j = 0; j < WD; ++j) {
                        const uint4v* hp = reinterpret_cast<const uint4v*>(hw + j * HID);
                        uint4v g[8];
                        #pragma unroll
                        for (int k = 0; k < 8; ++k) g[k] = hp[k];
                        po[j][L * 4 + pos] = dotrow(w[0], g, 0.f);
                    }
                }
            } else if (wv == 3) {
                if (p1act) {                   // wih1_o (c3 -> pos 2)
                    const _Float16* hw = &h0ring[(par ^ 1) * WD][0];
                    float (*po)[4 * HID] = p1buf[par ^ 1];
                    #pragma unroll
                    for (int j = 0; j < WD; ++j) {
                        const uint4v* hp = reinterpret_cast<const uint4v*>(hw + j * HID);
                        uint4v g[8];
                        #pragma unroll
                        for (int k = 0; k < 8; ++k) g[k] = hp[k];
                        po[j][L * 4 + 2] = dotrow(w[0], g, 0.f);
                    }
                }
                if (p2act) {                   // wih2_i (c0 -> pos 3)
                    const _Float16* hw = &h1ring[(par ^ 1) * WD][0];
                    float (*po)[4 * HID] = p2buf[par ^ 1];
                    #pragma unroll
                    for (int j = 0; j < WD; ++j) {
                        const uint4v* hp = reinterpret_cast<const uint4v*>(hw + j * HID);
                        uint4v g[8];
                        #pragma unroll
                        for (int k = 0; k < 8; ++k) g[k] = hp[k];
                        po[j][L * 4 + 3] = dotrow(w[1], g, 0.f);
                    }
                }
            } else {                           // wv == 7: wih2_{f,g,o}
                if (p2act) {
                    const _Float16* hw = &h1ring[(par ^ 1) * WD][0];
                    float (*po)[4 * HID] = p2buf[par ^ 1];
                    #pragma unroll
                    for (int j = 0; j < WD; ++j) {
                        const uint4v* hp = reinterpret_cast<const uint4v*>(hw + j * HID);
                        uint4v g[8];
                        #pragma unroll
                        for (int k = 0; k < 8; ++k) g[k] = hp[k];
                        float pf = dotrow(w[0], g, 0.f);   // c1 -> pos 0
                        float pg = dotrow(w[1], g, 0.f);   // c2 -> pos 1
                        float po3 = dotrow(w[2], g, 0.f);  // c3 -> pos 2
                        // pos 0,1 at dword L*4 -> 8B-aligned pair: one b64.
                        *reinterpret_cast<float2*>(&po[j][L * 4]) =
                            make_float2(pf, pg);
                        po[j][L * 4 + 2] = po3;
                    }
                }
            }
        }

        __syncthreads();   // publish window: h rings + p-buffers
    }

    // Final FC (f32): h2[2047] -> window step 7 -> slot 7&1 = 1.
    if (tid < EMB) {
        float acc = fcb[tid];
        const _Float16* hf = &h2ring[1][0];
        const float4* W4 = reinterpret_cast<const float4*>(fcW + tid * HID);
        #pragma unroll
        for (int k = 0; k < 16; ++k) {
            float4 wv4 = W4[k];
            acc = fmaf(wv4.x, (float)hf[4 * k + 0], acc);
            acc = fmaf(wv4.y, (float)hf[4 * k + 1], acc);
            acc = fmaf(wv4.z, (float)hf[4 * k + 2], acc);
            acc = fmaf(wv4.w, (float)hf[4 * k + 3], acc);
        }
        out[b * EMB + tid] = acc;
    }
}

extern "C" void kernel_launch(void* const* d_in, const int* in_sizes, int n_in,
                              void* d_out, int out_size, void* d_ws, size_t ws_size,
                              hipStream_t stream) {
    const float* x    = (const float*)d_in[0];
    const float* Wih0 = (const float*)d_in[1];
    const float* Whh0 = (const float*)d_in[2];
    const float* bih0 = (const float*)d_in[3];
    const float* bhh0 = (const float*)d_in[4];
    const float* Wih1 = (const float*)d_in[5];
    const float* Whh1 = (const float*)d_in[6];
    const float* bih1 = (const float*)d_in[7];
    const float* bhh1 = (const float*)d_in[8];
    const float* Wih2 = (const float*)d_in[9];
    const float* Whh2 = (const float*)d_in[10];
    const float* bih2 = (const float*)d_in[11];
    const float* bhh2 = (const float*)d_in[12];
    const float* fcW  = (const float*)d_in[13];
    const float* fcb  = (const float*)d_in[14];
    float* out = (float*)d_out;

    lstm3_fused<<<dim3(256), dim3(512), 0, stream>>>(
        x, Wih0, Whh0, bih0, bhh0,
        Wih1, Whh1, bih1, bhh1,
        Wih2, Whh2, bih2, bhh2,
        fcW, fcb, out);
}